// Round 1
// baseline (6671.493 us; speedup 1.0000x reference)
//
#include <hip/hip_runtime.h>
#include <hip/hip_bf16.h>

#define HID 256
#define NH 4
#define DH 64
#define MAXL 128
#define QK_STRIDE 68   // bf16 elems; 136 B rows: 8B-aligned, 2-way-max bank aliasing on b64 reads
#define V_STRIDE 132   // bf16 elems; 264 B rows: 8B-aligned, 2-way-max bank aliasing

typedef __hip_bfloat16 bf16;

__device__ __forceinline__ float bflo(unsigned u) { return __uint_as_float(u << 16); }
__device__ __forceinline__ float bfhi(unsigned u) { return __uint_as_float(u & 0xffff0000u); }

#define FMA4(acc, xv, wv)                                                     \
  acc = fmaf((xv).x, (wv).x,                                                  \
        fmaf((xv).y, (wv).y, fmaf((xv).z, (wv).z, fmaf((xv).w, (wv).w, (acc)))))

// One block per (molecule, head). Computes q,k,v (fp32 dots -> bf16 LDS),
// attention + softmax + PV + ReLU, writes o_relu slice to O[total][256] (bf16 ws).
__global__ __launch_bounds__(256, 2) void attn_kernel(
    const float* __restrict__ msg,
    const float* __restrict__ Wq,
    const float* __restrict__ Wk,
    const float* __restrict__ Wv,
    const int* __restrict__ starts,
    const int* __restrict__ sizes,
    bf16* __restrict__ O)
{
  const int mol  = blockIdx.x >> 2;
  const int head = blockIdx.x & 3;
  const int L     = sizes[mol];
  const int start = starts[mol];

  __shared__ __align__(16) bf16 q_s[MAXL][QK_STRIDE];
  __shared__ __align__(16) bf16 k_s[MAXL][QK_STRIDE];
  __shared__ __align__(16) bf16 v_t[DH][V_STRIDE];   // transposed: [d][l]
  __shared__ __align__(16) float p_s[4][MAXL];

  const int tid  = threadIdx.x;
  const int wave = tid >> 6;
  const int lane = tid & 63;
  const int g = head * DH + lane;

  const float* __restrict__ wq = Wq + (size_t)g * HID;
  const float* __restrict__ wk = Wk + (size_t)g * HID;
  const float* __restrict__ wv = Wv + (size_t)g * HID;

  // ---- Step 1: q,k,v for all rows; 4 rows per pass per wave (amortize weight loads) ----
  for (int l0 = wave * 4; l0 < L; l0 += 16) {
    float aq[4] = {0.f,0.f,0.f,0.f}, ak[4] = {0.f,0.f,0.f,0.f}, av[4] = {0.f,0.f,0.f,0.f};
    const float* xr[4];
    #pragma unroll
    for (int r = 0; r < 4; r++) {
      int l = l0 + r; if (l >= L) l = L - 1;   // clamped rows computed, not stored
      xr[r] = msg + (size_t)(start + l) * HID;
    }
    #pragma unroll 4
    for (int f = 0; f < HID; f += 4) {
      float4 wqv = *(const float4*)(wq + f);
      float4 wkv = *(const float4*)(wk + f);
      float4 wvv = *(const float4*)(wv + f);
      #pragma unroll
      for (int r = 0; r < 4; r++) {
        float4 xv = *(const float4*)(xr[r] + f);
        FMA4(aq[r], xv, wqv);
        FMA4(ak[r], xv, wkv);
        FMA4(av[r], xv, wvv);
      }
    }
    #pragma unroll
    for (int r = 0; r < 4; r++) {
      int l = l0 + r;
      if (l < L) {
        q_s[l][lane] = __float2bfloat16(aq[r]);
        k_s[l][lane] = __float2bfloat16(ak[r]);
        v_t[lane][l] = __float2bfloat16(av[r]);
      }
    }
  }
  // zero-pad v columns up to multiple of 4 so PV's tail reads are 0 (never NaN)
  {
    int Lpad = (L + 3) & ~3;
    for (int l = L + wave; l < Lpad; l += 4) v_t[lane][l] = __float2bfloat16(0.f);
  }
  __syncthreads();

  // ---- Step 2: per-query-row attention; wave w owns rows lq = w, w+4, ... ----
  const float scale = 0.125f;  // DH^-0.5
  for (int lq = wave; lq < L; lq += 4) {
    // scores: lane computes s for key j=lane and j=lane+64
    int j0 = lane      < L ? lane      : L - 1;
    int j1 = lane + 64 < L ? lane + 64 : L - 1;
    const uint2* qrow  = (const uint2*)q_s[lq];
    const uint2* krow0 = (const uint2*)k_s[j0];
    const uint2* krow1 = (const uint2*)k_s[j1];
    float s0 = 0.f, s1 = 0.f;
    #pragma unroll
    for (int c = 0; c < DH / 4; c++) {
      uint2 qu = qrow[c];
      float q0 = bflo(qu.x), q1 = bfhi(qu.x), q2 = bflo(qu.y), q3 = bfhi(qu.y);
      uint2 ka = krow0[c];
      s0 = fmaf(q0, bflo(ka.x), s0); s0 = fmaf(q1, bfhi(ka.x), s0);
      s0 = fmaf(q2, bflo(ka.y), s0); s0 = fmaf(q3, bfhi(ka.y), s0);
      uint2 kb = krow1[c];
      s1 = fmaf(q0, bflo(kb.x), s1); s1 = fmaf(q1, bfhi(kb.x), s1);
      s1 = fmaf(q2, bflo(kb.y), s1); s1 = fmaf(q3, bfhi(kb.y), s1);
    }
    s0 = (lane      < L) ? s0 * scale : -INFINITY;
    s1 = (lane + 64 < L) ? s1 * scale : -INFINITY;

    // softmax over 128 slots (invalid -> 0)
    float m = fmaxf(s0, s1);
    #pragma unroll
    for (int off = 32; off; off >>= 1) m = fmaxf(m, __shfl_xor(m, off));
    float e0 = (lane      < L) ? __expf(s0 - m) : 0.f;
    float e1 = (lane + 64 < L) ? __expf(s1 - m) : 0.f;
    float sum = e0 + e1;
    #pragma unroll
    for (int off = 32; off; off >>= 1) sum += __shfl_xor(sum, off);
    float inv = 1.f / sum;
    p_s[wave][lane]      = e0 * inv;
    p_s[wave][lane + 64] = e1 * inv;
    // same-wave LDS write->read is in-order; no barrier needed

    // PV: lane = d; o = sum_j p[j] * v[j][d] using transposed V (j-contiguous)
    const uint2* vrow = (const uint2*)v_t[lane];
    const float* prow = p_s[wave];
    float o = 0.f;
    int C = (L + 3) >> 2;
    for (int c = 0; c < C; c++) {
      uint2 vu = vrow[c];
      float4 pv = *(const float4*)(prow + c * 4);
      o = fmaf(pv.x, bflo(vu.x), o); o = fmaf(pv.y, bfhi(vu.x), o);
      o = fmaf(pv.z, bflo(vu.y), o); o = fmaf(pv.w, bfhi(vu.y), o);
    }
    float ov = fmaxf(o, 0.f);  // ReLU
    O[(size_t)(start + lq) * HID + head * DH + lane] = __float2bfloat16(ov);
  }
}

// Out-projection (y = o_relu @ Wo^T + bo) + LayerNorm + write fp32 out.
// Block = 256 thr = 4 waves; each wave register-blocks 8 rows; block covers 32 rows.
__global__ __launch_bounds__(256, 2) void proj_ln_kernel(
    const bf16* __restrict__ O,
    const float* __restrict__ Wo,
    const float* __restrict__ bo,
    const float* __restrict__ gamma,
    const float* __restrict__ beta,
    float* __restrict__ out,
    int total)
{
  __shared__ __align__(16) float o_s[32][HID];   // 32 KB
  const int base = blockIdx.x * 32;
  const int tid  = threadIdx.x;
  const int wave = tid >> 6;
  const int lane = tid & 63;

  // cooperative load: 32 rows x 256 bf16, 4 elems (uint2) per thread-iter
  for (int i = tid; i < 32 * HID / 4; i += 256) {
    int row_local = i >> 6;
    int col = (i & 63) * 4;
    int row = base + row_local; if (row >= total) row = total - 1;
    uint2 u = *(const uint2*)(O + (size_t)row * HID + col);
    *(float4*)&o_s[row_local][col] =
        make_float4(bflo(u.x), bfhi(u.x), bflo(u.y), bfhi(u.y));
  }
  __syncthreads();

  const int r0 = wave * 8;
  float acc[4][8];
  #pragma unroll
  for (int gi = 0; gi < 4; gi++) {
    const int gg = gi * 64 + lane;
    const float* __restrict__ wrow = Wo + (size_t)gg * HID;
    float b = bo[gg];
    float a[8];
    #pragma unroll
    for (int r = 0; r < 8; r++) a[r] = b;
    for (int f = 0; f < HID; f += 4) {
      float4 wv = *(const float4*)(wrow + f);
      #pragma unroll
      for (int r = 0; r < 8; r++) {
        float4 ov = *(const float4*)&o_s[r0 + r][f];  // LDS broadcast
        FMA4(a[r], ov, wv);
      }
    }
    #pragma unroll
    for (int r = 0; r < 8; r++) acc[gi][r] = a[r];
  }

  float gmm[4], bt[4];
  #pragma unroll
  for (int gi = 0; gi < 4; gi++) { gmm[gi] = gamma[gi * 64 + lane]; bt[gi] = beta[gi * 64 + lane]; }

  #pragma unroll
  for (int r = 0; r < 8; r++) {
    int row = base + r0 + r;
    float s  = acc[0][r] + acc[1][r] + acc[2][r] + acc[3][r];
    float ss = acc[0][r]*acc[0][r] + acc[1][r]*acc[1][r]
             + acc[2][r]*acc[2][r] + acc[3][r]*acc[3][r];
    #pragma unroll
    for (int off = 32; off; off >>= 1) { s += __shfl_xor(s, off); ss += __shfl_xor(ss, off); }
    float mu  = s * (1.f / HID);
    float var = ss * (1.f / HID) - mu * mu;
    float invs = rsqrtf(var + 1e-5f);
    if (row < total) {
      if (row == 0) {
        #pragma unroll
        for (int gi = 0; gi < 4; gi++) out[gi * 64 + lane] = 0.f;  // cached_zero_vector row
      } else {
        #pragma unroll
        for (int gi = 0; gi < 4; gi++) {
          int gg = gi * 64 + lane;
          out[(size_t)row * HID + gg] = (acc[gi][r] - mu) * invs * gmm[gi] + bt[gi];
        }
      }
    }
  }
}

extern "C" void kernel_launch(void* const* d_in, const int* in_sizes, int n_in,
                              void* d_out, int out_size, void* d_ws, size_t ws_size,
                              hipStream_t stream) {
  const float* msg   = (const float*)d_in[0];
  const float* Wq    = (const float*)d_in[1];
  const float* Wk    = (const float*)d_in[2];
  const float* Wv    = (const float*)d_in[3];
  const float* Wo    = (const float*)d_in[4];
  const float* bo    = (const float*)d_in[5];
  const float* gamma = (const float*)d_in[6];
  const float* beta  = (const float*)d_in[7];
  const int* starts  = (const int*)d_in[8];
  const int* sizes   = (const int*)d_in[9];

  const int nmols = in_sizes[8];
  const int total = in_sizes[0] / HID;

  bf16* O = (bf16*)d_ws;  // [total][HID] bf16 o_relu scratch (~84 MB)

  attn_kernel<<<nmols * NH, 256, 0, stream>>>(msg, Wq, Wk, Wv, starts, sizes, O);
  proj_ln_kernel<<<(total + 31) / 32, 256, 0, stream>>>(
      O, Wo, bo, gamma, beta, (float*)d_out, total);
}

// Round 2
// 1229.712 us; speedup vs baseline: 5.4252x; 5.4252x over previous
//
#include <hip/hip_runtime.h>
#include <hip/hip_bf16.h>

#define HID 256
#define NH 4
#define DH 64

typedef __attribute__((ext_vector_type(8))) short bf16x8;
typedef __attribute__((ext_vector_type(4))) float f32x4;

#define MFMA16(a, b, c) __builtin_amdgcn_mfma_f32_16x16x32_bf16((a), (b), (c), 0, 0, 0)

// LDS row strides (bf16 elems); all give 16B-aligned rows, stride%32dw==4 (2-way max aliasing)
#define LQK 72
#define LVT 136
#define LPB 136

__device__ __forceinline__ short f2bf(float f) {       // RNE fp32->bf16 (finite inputs)
  unsigned u = __float_as_uint(f);
  unsigned r = (u + 0x7fffu + ((u >> 16) & 1u)) >> 16;
  return (short)r;
}

__device__ __forceinline__ bf16x8 ld_cvt8(const float* p) {  // 8 fp32 -> bf16x8
  float4 a = *(const float4*)p;
  float4 b = *(const float4*)(p + 4);
  bf16x8 r;
  r[0] = f2bf(a.x); r[1] = f2bf(a.y); r[2] = f2bf(a.z); r[3] = f2bf(a.w);
  r[4] = f2bf(b.x); r[5] = f2bf(b.y); r[6] = f2bf(b.z); r[7] = f2bf(b.w);
  return r;
}

// One block per (molecule, head); 4 waves. MFMA QKV + flash-style attention.
// A-frag: A[m=lane&15][k=(lane>>4)*8+j]; B-frag: B^T rows, n=lane&15, same k pattern.
// C/D:    D[row=(lane>>4)*4+reg][col=lane&15]   (m89/m91-verified layouts)
__global__ __launch_bounds__(256) void attn_kernel(
    const float* __restrict__ msg, const float* __restrict__ Wq,
    const float* __restrict__ Wk, const float* __restrict__ Wv,
    const int* __restrict__ starts, const int* __restrict__ sizes,
    short* __restrict__ O)
{
  __shared__ __align__(16) short K_s[128 * LQK];      // K rows (B-operand for QK^T)
  __shared__ __align__(16) short V_t[DH * LVT];       // V transposed (B-operand for PV)
  __shared__ __align__(16) short P_s[4 * 16 * LPB];   // per-wave Q-scratch / P transpose

  const int mol  = blockIdx.x >> 2;
  const int head = blockIdx.x & 3;
  const int L     = sizes[mol];
  const int start = starts[mol];
  const int Mt  = (L + 15) >> 4;        // 16-row q tiles (2..8)
  const int NtE = Mt + (Mt & 1);        // key-tile count rounded even (PV k-step = 32)

  const int tid  = threadIdx.x;
  const int wave = tid >> 6;
  const int lane = tid & 63;
  const int c = lane & 15;              // "n"/"m" index within tile
  const int g = lane >> 4;              // k-quad / row-quad
  short* Pw = P_s + wave * (16 * LPB);

  // zero V_t pad columns [Mt*16, Mt*16+16) when Mt odd (PV reads NtE*16 cols)
  if (Mt & 1) {
    unsigned* vz = (unsigned*)V_t;
    for (int f = tid; f < DH * 8; f += 256)
      vz[(f >> 3) * (LVT / 2) + Mt * 8 + (f & 7)] = 0u;
  }

  const int mt0 = wave, mt1 = wave + 4;
  const bool h0 = mt0 < Mt, h1 = mt1 < Mt;
  bf16x8 qf[2][2];                       // Q A-frags (K=64 -> 2 k-steps) per owned m-tile

  // ================= Phase 1: QKV projection (MFMA) =================
  if (h0) {
    bf16x8 a0[8], a1[8];                 // X A-frags, 8 k-steps of K=256
    const bf16x8 zf = {0, 0, 0, 0, 0, 0, 0, 0};
    {
      int rl = mt0 * 16 + c;
      bool v = rl < L;
      const float* xp = msg + (size_t)(start + (v ? rl : 0)) * HID + g * 8;
      #pragma unroll
      for (int ks = 0; ks < 8; ks++) { bf16x8 t = ld_cvt8(xp + ks * 32); a0[ks] = v ? t : zf; }
    }
    if (h1) {
      int rl = mt1 * 16 + c;
      bool v = rl < L;
      const float* xp = msg + (size_t)(start + (v ? rl : 0)) * HID + g * 8;
      #pragma unroll
      for (int ks = 0; ks < 8; ks++) { bf16x8 t = ld_cvt8(xp + ks * 32); a1[ks] = v ? t : zf; }
    }

    const float* Wsec[3] = {Wq, Wk, Wv};
    #pragma unroll
    for (int nt = 0; nt < 12; nt++) {    // 192 output cols: q(0-3) k(4-7) v(8-11)
      const float* Wp = Wsec[nt >> 2] + (size_t)(head * 64 + (nt & 3) * 16 + c) * HID + g * 8;
      bf16x8 b[8];
      #pragma unroll
      for (int ks = 0; ks < 8; ks++) b[ks] = ld_cvt8(Wp + ks * 32);

      #pragma unroll
      for (int i = 0; i < 2; i++) {
        if (i == 1 && !h1) continue;
        f32x4 acc = {0.f, 0.f, 0.f, 0.f};
        #pragma unroll
        for (int ks = 0; ks < 8; ks++)
          acc = MFMA16((i == 0 ? a0[ks] : a1[ks]), b[ks], acc);
        const int mt = (i == 0) ? mt0 : mt1;
        #pragma unroll
        for (int r = 0; r < 4; r++) {
          short val = f2bf(acc[r]);
          int row = mt * 16 + g * 4 + r;                    // < Mt*16 always
          if (nt < 4)       Pw[(g * 4 + r) * LPB + i * 64 + nt * 16 + c] = val;   // Q scratch
          else if (nt < 8)  K_s[row * LQK + (nt - 4) * 16 + c] = val;             // K row-major
          else              V_t[((nt - 8) * 16 + c) * LVT + row] = val;           // V transposed
        }
      }
      if (nt == 3) {                      // Q written -> pull A-operand frags
        __threadfence_block();
        #pragma unroll
        for (int i = 0; i < 2; i++)
          #pragma unroll
          for (int ks = 0; ks < 2; ks++)
            qf[i][ks] = *(const bf16x8*)&Pw[c * LPB + i * 64 + ks * 32 + g * 8];
      }
    }
  }
  __syncthreads();   // uniform: all K_s / V_t visible

  // ================= Phase 2: attention per owned q-tile =================
  const float scale = 0.125f;  // DH^-0.5
  #pragma unroll
  for (int i = 0; i < 2; i++) {
    int mt = wave + 4 * i;
    if (mt >= Mt) continue;

    // ---- S = Q K^T (C-layout in regs) ----
    float sv[8][4];
    #pragma unroll
    for (int nt = 0; nt < 8; nt++) {
      if (nt < NtE) {
        f32x4 acc = {0.f, 0.f, 0.f, 0.f};
        #pragma unroll
        for (int ks = 0; ks < 2; ks++) {
          bf16x8 kb = *(const bf16x8*)&K_s[(nt * 16 + c) * LQK + ks * 32 + g * 8];
          acc = MFMA16(qf[i][ks], kb, acc);
        }
        sv[nt][0] = acc[0]; sv[nt][1] = acc[1]; sv[nt][2] = acc[2]; sv[nt][3] = acc[3];
      }
    }

    // ---- softmax per row (row = g*4+r lives in lanes [g*16, g*16+16)) ----
    const bool colv = true;
    #pragma unroll
    for (int r = 0; r < 4; r++) {
      float mr = -3.0e38f;
      #pragma unroll
      for (int nt = 0; nt < 8; nt++) {
        if (nt < NtE) {
          bool valid = (nt * 16 + c) < L;
          float v = valid ? sv[nt][r] * scale : -3.0e38f;
          sv[nt][r] = v;
          mr = fmaxf(mr, v);
        }
      }
      mr = fmaxf(mr, __shfl_xor(mr, 1));
      mr = fmaxf(mr, __shfl_xor(mr, 2));
      mr = fmaxf(mr, __shfl_xor(mr, 4));
      mr = fmaxf(mr, __shfl_xor(mr, 8));
      float sum = 0.f;
      #pragma unroll
      for (int nt = 0; nt < 8; nt++) {
        if (nt < NtE) {
          float e = (sv[nt][r] > -1.0e37f) ? __expf(sv[nt][r] - mr) : 0.f;
          sv[nt][r] = e;
          sum += e;
        }
      }
      sum += __shfl_xor(sum, 1);
      sum += __shfl_xor(sum, 2);
      sum += __shfl_xor(sum, 4);
      sum += __shfl_xor(sum, 8);
      float inv = 1.f / sum;
      #pragma unroll
      for (int nt = 0; nt < 8; nt++)
        if (nt < NtE)
          Pw[(g * 4 + r) * LPB + nt * 16 + c] = f2bf(sv[nt][r] * inv);
    }
    __threadfence_block();   // P transpose round-trip, same wave

    // ---- O = P V, ReLU, store bf16 to ws ----
    #pragma unroll
    for (int nt2 = 0; nt2 < 4; nt2++) {
      f32x4 acc = {0.f, 0.f, 0.f, 0.f};
      #pragma unroll
      for (int ks = 0; ks < 4; ks++) {
        if (ks * 2 < NtE) {
          bf16x8 pa = *(const bf16x8*)&Pw[c * LPB + ks * 32 + g * 8];
          bf16x8 vb = *(const bf16x8*)&V_t[(nt2 * 16 + c) * LVT + ks * 32 + g * 8];
          acc = MFMA16(pa, vb, acc);
        }
      }
      #pragma unroll
      for (int r = 0; r < 4; r++) {
        int rl = mt * 16 + g * 4 + r;
        if (rl < L)
          O[(size_t)(start + rl) * HID + head * 64 + nt2 * 16 + c] =
              f2bf(fmaxf(acc[r], 0.f));
      }
    }
  }
}

// MFMA out-projection + bias + LayerNorm. Block = 32 rows, wave owns 64 cols.
__global__ __launch_bounds__(256) void proj_ln_kernel(
    const short* __restrict__ Ob, const float* __restrict__ Wo,
    const float* __restrict__ bo, const float* __restrict__ gamma,
    const float* __restrict__ beta, float* __restrict__ out, int total)
{
  __shared__ __align__(16) float o_s[32 * 260];   // 33.3 KB, stride 260 (1040B, 16B-aligned)
  const int base = blockIdx.x * 32;
  const int tid  = threadIdx.x;
  const int wave = tid >> 6;
  const int lane = tid & 63;
  const int c = lane & 15, g = lane >> 4;

  // A-frags from O (already bf16)
  bf16x8 a[2][8];
  #pragma unroll
  for (int i = 0; i < 2; i++) {
    int row = base + i * 16 + c;
    if (row >= total) row = total - 1;
    const short* p = Ob + (size_t)row * HID + g * 8;
    #pragma unroll
    for (int ks = 0; ks < 8; ks++) a[i][ks] = *(const bf16x8*)(p + ks * 32);
  }

  #pragma unroll
  for (int nt = 0; nt < 4; nt++) {
    const float* Wp = Wo + (size_t)(wave * 64 + nt * 16 + c) * HID + g * 8;
    bf16x8 b[8];
    #pragma unroll
    for (int ks = 0; ks < 8; ks++) b[ks] = ld_cvt8(Wp + ks * 32);
    #pragma unroll
    for (int i = 0; i < 2; i++) {
      f32x4 acc = {0.f, 0.f, 0.f, 0.f};
      #pragma unroll
      for (int ks = 0; ks < 8; ks++) acc = MFMA16(a[i][ks], b[ks], acc);
      #pragma unroll
      for (int r = 0; r < 4; r++)
        o_s[(i * 16 + g * 4 + r) * 260 + wave * 64 + nt * 16 + c] = acc[r];
    }
  }
  __syncthreads();

  // LayerNorm: wave handles 8 rows; lane covers 4 cols
  float4 bo4 = *(const float4*)(bo + lane * 4);
  float4 g4  = *(const float4*)(gamma + lane * 4);
  float4 b4  = *(const float4*)(beta + lane * 4);
  #pragma unroll
  for (int r8 = 0; r8 < 8; r8++) {
    int rl = wave * 8 + r8;
    float4 o = *(const float4*)&o_s[rl * 260 + lane * 4];
    o.x += bo4.x; o.y += bo4.y; o.z += bo4.z; o.w += bo4.w;
    float s  = o.x + o.y + o.z + o.w;
    float ss = o.x * o.x + o.y * o.y + o.z * o.z + o.w * o.w;
    #pragma unroll
    for (int off = 32; off; off >>= 1) { s += __shfl_xor(s, off); ss += __shfl_xor(ss, off); }
    float mu  = s * (1.f / HID);
    float var = ss * (1.f / HID) - mu * mu;
    float inv = rsqrtf(var + 1e-5f);
    int row = base + rl;
    if (row < total) {
      float4 res;
      res.x = (o.x - mu) * inv * g4.x + b4.x;
      res.y = (o.y - mu) * inv * g4.y + b4.y;
      res.z = (o.z - mu) * inv * g4.z + b4.z;
      res.w = (o.w - mu) * inv * g4.w + b4.w;
      if (row == 0) res = make_float4(0.f, 0.f, 0.f, 0.f);  // cached_zero_vector
      *(float4*)(out + (size_t)row * HID + lane * 4) = res;
    }
  }
}

extern "C" void kernel_launch(void* const* d_in, const int* in_sizes, int n_in,
                              void* d_out, int out_size, void* d_ws, size_t ws_size,
                              hipStream_t stream) {
  const float* msg   = (const float*)d_in[0];
  const float* Wq    = (const float*)d_in[1];
  const float* Wk    = (const float*)d_in[2];
  const float* Wv    = (const float*)d_in[3];
  const float* Wo    = (const float*)d_in[4];
  const float* bo    = (const float*)d_in[5];
  const float* gamma = (const float*)d_in[6];
  const float* beta  = (const float*)d_in[7];
  const int* starts  = (const int*)d_in[8];
  const int* sizes   = (const int*)d_in[9];

  const int nmols = in_sizes[8];
  const int total = in_sizes[0] / HID;

  short* O = (short*)d_ws;  // [total][HID] bf16 o_relu scratch (~84 MB, proven fits)

  attn_kernel<<<nmols * NH, 256, 0, stream>>>(msg, Wq, Wk, Wv, starts, sizes, O);
  proj_ln_kernel<<<(total + 31) / 32, 256, 0, stream>>>(
      O, Wo, bo, gamma, beta, (float*)d_out, total);
}